// Round 6
// baseline (299.801 us; speedup 1.0000x reference)
//
#include <hip/hip_runtime.h>
#include <hip/hip_fp16.h>
#include <math.h>

#define GHH 224
#define GWW 224
#define HW (GHH*GWW)     // 50176
#define BATCH 8
#define RAD 3
#define DIAM 7
#define QC 32
#define TILE 16
#define TP (TILE + 2*RAD)   // 22
#define TPIX (TP*TP)        // 484
#define CS 485              // chunk-plane stride in float4 (proven layout)

// LDS layout: [hrh: 8 planes x 22 rows x 24 cols f16 = 8448 B][sq: 4*485*16 = 31040 B]
// hrh planes 0-3 = hi{x,y,z,1}, 4-7 = lo{x,y,z,0}. Total 39488 B (39936 alloc).
// 512-thread blocks: 4 blocks/CU x 8 waves = 32 waves/CU if VGPR<=64 (LDS-limited).
// launch_bounds(512,4): SOFT budget (128 VGPR) — same envelope R3 compiled at 52 VGPR
// under; avoids forcing the allocator to a hard 64 cap (suspected compile-stage failure
// of the (512,8) build).
#define HRH_COLS 24
#define PSTR (TP*HRH_COLS)   // 528 halves per plane
#define HRH_B (8*PSTR*2)     // 8448 B
#define SMEM_B (HRH_B + 4*CS*16)  // 39488

typedef _Float16 h2 __attribute__((ext_vector_type(2)));
typedef _Float16 v8h __attribute__((ext_vector_type(8)));
typedef float v4f __attribute__((ext_vector_type(4)));

__device__ __forceinline__ int refl(int i) {
    if (i < 0) i = -i;
    if (i >= GHH) i = 2 * GHH - 2 - i;
    return i;
}

__device__ __forceinline__ float gelu_fast(float v) {
    float u = 0.7978845608f * v * (1.f + 0.044715f * v * v);
    float e = __expf(2.f * u);
    float th = 1.f - 2.f / (e + 1.f);
    return 0.5f * v * (1.f + th);
}

// ---------------- linear + w2 B-frag prep + w1 f16 pack + guid4 pack ----------------
__global__ void linear_prep_kernel(const float* __restrict__ x,
                                   const float* __restrict__ W,
                                   const float* __restrict__ bias,
                                   float* __restrict__ f0,
                                   const float* __restrict__ w2s,
                                   __half* __restrict__ wsB,
                                   const float* __restrict__ w1s,
                                   const float* __restrict__ b1s,
                                   __half* __restrict__ wsW1,
                                   const float* __restrict__ guid,
                                   float4* __restrict__ guid4) {
    int blk = blockIdx.x;
    if (blk >= 1946) {   // guid4 pack: 1568 blocks
        int i = (blk - 1946) * 256 + threadIdx.x;
        int b = i / HW, pix = i % HW;
        guid4[i] = make_float4(guid[(b * 3) * HW + pix],
                               guid[(b * 3 + 1) * HW + pix],
                               guid[(b * 3 + 2) * HW + pix], 0.f);
        return;
    }
    if (blk == 1945) {   // pack w1/b1 (4 stages x 32 ch) into f16 quads (w0,w1,w2,b)
        int tid = threadIdx.x;
        if (tid < 128) {
            int s = tid >> 5, c = tid & 31;
            wsW1[tid * 4 + 0] = __float2half(w1s[s * 96 + c * 3 + 0]);
            wsW1[tid * 4 + 1] = __float2half(w1s[s * 96 + c * 3 + 1]);
            wsW1[tid * 4 + 2] = __float2half(w1s[s * 96 + c * 3 + 2]);
            wsW1[tid * 4 + 3] = __float2half(b1s[s * 32 + c]);
        }
        return;
    }
    if (blk == 1944) {   // pack w2 (4 stages) into f16 MFMA fragments
        int tid = threadIdx.x;
        int s = tid >> 6, l = tid & 63;
        int n0 = l & 15, kq = l >> 4;
        const float* w2 = w2s + s * 1024;
        __half* dst = wsB + (size_t)tid * 16;
        #pragma unroll
        for (int j = 0; j < 8; j++) {
            dst[j]     = __float2half(w2[n0 * QC + kq * 8 + j]);
            dst[8 + j] = __float2half(w2[(n0 + 16) * QC + kq * 8 + j]);
        }
        return;
    }
    int gwave = (blk * blockDim.x + threadIdx.x) >> 6;
    int lane = threadIdx.x & 63;
    if (gwave >= BATCH * 972) return;
    int b = gwave / 972, j = gwave % 972;
    const float* xr = x + b * 1000;
    const float* wr = W + j * 1000;
    float s = 0.f;
    for (int k = lane; k < 1000; k += 64)
        s += xr[k] * wr[k];
    #pragma unroll
    for (int off = 32; off; off >>= 1) s += __shfl_down(s, off, 64);
    if (lane == 0) f0[gwave] = s + bias[j];
}

// ---------------- bicubic 18 -> 224, float4-interleaved output ----------------
__device__ __forceinline__ float cubicw(float d) {
    d = fabsf(d);
    if (d <= 1.f) return ((1.25f * d - 2.25f) * d) * d + 1.f;
    if (d < 2.f)  return ((-0.75f * d + 3.75f) * d - 6.f) * d + 3.f;
    return 0.f;
}

__global__ void bicubic_kernel(const float* __restrict__ f0, float4* __restrict__ hr4) {
    int idx = blockIdx.x * blockDim.x + threadIdx.x;
    if (idx >= BATCH * HW) return;
    int pix = idx % HW;
    int b = idx / HW;
    int w = pix % GWW, h = pix / GWW;
    float xx = (w + 0.5f) * (18.f / 224.f) - 0.5f;
    float yy = (h + 0.5f) * (18.f / 224.f) - 0.5f;
    float fx0 = floorf(xx), fy0 = floorf(yy);
    int x0 = (int)fx0, y0 = (int)fy0;
    float tx = xx - fx0, ty = yy - fy0;
    float wx[4], wy[4];
    int ix[4], iy[4];
    #pragma unroll
    for (int k = 0; k < 4; k++) {
        wx[k] = cubicw(tx - (float)(k - 1));
        wy[k] = cubicw(ty - (float)(k - 1));
        int a = x0 + (k - 1); ix[k] = min(max(a, 0), 17);
        a = y0 + (k - 1);     iy[k] = min(max(a, 0), 17);
    }
    float acc[3];
    #pragma unroll
    for (int c = 0; c < 3; c++) {
        const float* src = f0 + (b * 3 + c) * 324;
        float a = 0.f;
        #pragma unroll
        for (int ky = 0; ky < 4; ky++) {
            float rowv = 0.f;
            #pragma unroll
            for (int kx = 0; kx < 4; kx++) rowv += wx[kx] * src[iy[ky] * 18 + ix[kx]];
            a += wy[ky] * rowv;
        }
        acc[c] = a;
    }
    hr4[idx] = make_float4(acc[0], acc[1], acc[2], 0.f);
}

// ---------------- fused JBU: MFMA scores + MFMA conv, 512-thread blocks ----------------
// Identical math to R3 (bitwise-same output); 8 waves/block, each wave owns 2 center
// rows (rr 0..1, row = wv*2+rr). Occupancy 16 -> up to 32 waves/CU.
__global__ __launch_bounds__(512, 4) void jbu_kernel(
    const float4* __restrict__ guid4,
    const __half* __restrict__ wsW1,
    const __half* __restrict__ wsB, const float* __restrict__ b2,
    const float4* __restrict__ hr4,
    float4* __restrict__ out4,
    float* __restrict__ outP,
    const float* __restrict__ temps,
    const float* __restrict__ sigmas,
    int stage)
{
    __shared__ __align__(16) char smem[SMEM_B];
    _Float16* hrh = (_Float16*)smem;            // [8][22][24] f16
    char* sqb = smem + HRH_B;                   // q tile f16 chunk-planar [4][CS] float4

    const int tx = threadIdx.x, ty = threadIdx.y;   // 16 x 32
    const int tid = ty * 16 + tx;                   // 0..511
    const int b = blockIdx.z;
    const int h0 = blockIdx.y * TILE, w0 = blockIdx.x * TILE;

    // ---- stage hr tile as f16 hi/lo, channel-planar (+ ones / zeros planes) ----
    for (int i = tid; i < TPIX; i += 512) {
        int r = i / TP, cx = i % TP;
        int gh = refl(h0 - RAD + r), gw = refl(w0 - RAD + cx);
        float4 v = hr4[(size_t)b * HW + (size_t)gh * GWW + gw];
        _Float16 hx = (_Float16)v.x, hy = (_Float16)v.y, hz = (_Float16)v.z;
        int base = r * HRH_COLS + cx;
        hrh[0 * PSTR + base] = hx;
        hrh[1 * PSTR + base] = hy;
        hrh[2 * PSTR + base] = hz;
        hrh[3 * PSTR + base] = (_Float16)1.0f;
        hrh[4 * PSTR + base] = (_Float16)(v.x - (float)hx);
        hrh[5 * PSTR + base] = (_Float16)(v.y - (float)hy);
        hrh[6 * PSTR + base] = (_Float16)(v.z - (float)hz);
        hrh[7 * PSTR + base] = (_Float16)0.0f;
    }
    // zero pad cols 22,23 (read by masked-0 weights; must be finite, not LDS residue)
    for (int i = tid; i < 8 * TP * 2; i += 512) {
        int p = i / (TP * 2), rem = i % (TP * 2);
        int r = rem >> 1, cc = 22 + (rem & 1);
        hrh[p * PSTR + r * HRH_COLS + cc] = (_Float16)0.0f;
    }

    // ---- phase 0: q tile (validated path; 8 waves x 4 iters x 16 px = 512 slots) ----
    const int w = tid >> 6, l = tid & 63;     // w in 0..7
    const int n0 = l & 15, kq = l >> 4;
    const v8h* Bp = (const v8h*)(wsB + ((size_t)stage * 64 + l) * 16);
    const v8h W2a = Bp[0], W2b = Bp[1];
    const float4 b2a = *(const float4*)(b2 + 4 * kq);
    const float4 b2b = *(const float4*)(b2 + 16 + 4 * kq);
    union { _Float16 h[32]; float4 f4[4]; } W1;
    {
        const float4* wp = (const float4*)(wsW1 + stage * 128 + kq * 32);
        W1.f4[0] = wp[0]; W1.f4[1] = wp[1]; W1.f4[2] = wp[2]; W1.f4[3] = wp[3];
    }
    const int plane0 = kq >> 1;
    const int boff   = (kq & 1) * 8;

    #pragma unroll 1
    for (int r2 = 0; r2 < 2; r2++) {
        #pragma unroll
        for (int tt = 0; tt < 2; tt++) {
            int base = r2 * 256 + tt * 128 + w * 16;
            int p = base + n0;
            int pc = min(p, TPIX - 1);
            int rr = pc / TP, cc = pc - rr * TP;
            int gh = refl(h0 - RAD + rr), gw = refl(w0 - RAD + cc);
            float4 g = guid4[(size_t)b * HW + (size_t)gh * GWW + gw];
            union { _Float16 h[8]; v8h v; } A;
            #pragma unroll
            for (int j = 0; j < 8; j++) {
                float vv = fmaf((float)W1.h[j * 4], g.x,
                           fmaf((float)W1.h[j * 4 + 1], g.y,
                           fmaf((float)W1.h[j * 4 + 2], g.z, (float)W1.h[j * 4 + 3])));
                A.h[j] = (_Float16)gelu_fast(vv);
            }
            v4f D0 = {0.f, 0.f, 0.f, 0.f}, D1 = {0.f, 0.f, 0.f, 0.f};
            D0 = __builtin_amdgcn_mfma_f32_16x16x32_f16(W2a, A.v, D0, 0, 0, 0);
            D1 = __builtin_amdgcn_mfma_f32_16x16x32_f16(W2b, A.v, D1, 0, 0, 0);
            if (p < TPIX) {
                union { _Float16 h[4]; uint2 u; } q0, q1;
                q0.h[0] = (_Float16)(D0[0] + b2a.x);
                q0.h[1] = (_Float16)(D0[1] + b2a.y);
                q0.h[2] = (_Float16)(D0[2] + b2a.z);
                q0.h[3] = (_Float16)(D0[3] + b2a.w);
                q1.h[0] = (_Float16)(D1[0] + b2b.x);
                q1.h[1] = (_Float16)(D1[1] + b2b.y);
                q1.h[2] = (_Float16)(D1[2] + b2b.z);
                q1.h[3] = (_Float16)(D1[3] + b2b.w);
                *(uint2*)(sqb + (plane0 * CS + p) * 16 + boff)       = q0.u;
                *(uint2*)(sqb + ((2 + plane0) * CS + p) * 16 + boff) = q1.u;
            }
        }
    }
    __syncthreads();   // hrh + sq ready

    // ---- streaming: MFMA scores -> exp weights -> MFMA conv (R3-validated) ----
    const int wv = tid >> 6;               // 0..7, owns center rows wv*2, wv*2+1
    const int g = l >> 4, c = l & 15;      // g = k-chunk group, c = center col

    float t = __expf(temps[stage]);
    t = fminf(fmaxf(t, 1e-4f), 1e4f);
    float sig = sigmas[stage];
    float inv2s2 = 1.f / (2.f * sig * sig);
    float sdv[DIAM];
    #pragma unroll
    for (int i = 0; i < DIAM; i++) {
        float d = (float)(i - 3) * (1.f / 3.f);
        sdv[i] = __expf(-d * d * inv2s2);
    }
    // lc[jj]: ln(spatial_x) for tap k = 8g+jj at center c; -1e38 masks dj outside [0,6]
    float lc[8];
    #pragma unroll
    for (int jj = 0; jj < 8; jj++) {
        int dj = 8 * g + jj - c;
        float d = (float)(dj - 3) * (1.f / 3.f);
        lc[jj] = (dj >= 0 && dj <= 6) ? (-d * d * inv2s2) : -1e38f;
    }
    // neighbor-col loads (per lane, m = c): sigma_cb(c) clamped to row end
    const int nbb = 8 * (c >> 2) + (c & 3);
    const int nb0 = min(nbb, 21);
    const int nb1 = min(nbb + 4, 21);
    const int pA = c & 3;                  // hr channel plane for conv A-frag

    #pragma unroll 1
    for (int rr = 0; rr < 2; rr++) {
        const int row = wv * 2 + rr;
        // center B-frag (reused across di/cb): q[center row][col c][chunk g]
        const v8h Bc = *(const v8h*)(sqb + (size_t)(g * CS + (row + RAD) * TP + RAD + c) * 16);
        v4f D2 = {0.f, 0.f, 0.f, 0.f};
        #pragma unroll
        for (int di = 0; di < DIAM; di++) {
            const int prow = row + di;
            const v8h A0 = *(const v8h*)(sqb + (size_t)(g * CS + prow * TP + nb0) * 16);
            const v8h A1 = *(const v8h*)(sqb + (size_t)(g * CS + prow * TP + nb1) * 16);
            v4f S0 = {0.f, 0.f, 0.f, 0.f}, S1 = {0.f, 0.f, 0.f, 0.f};
            S0 = __builtin_amdgcn_mfma_f32_16x16x32_f16(A0, Bc, S0, 0, 0, 0);
            S1 = __builtin_amdgcn_mfma_f32_16x16x32_f16(A1, Bc, S1, 0, 0, 0);
            const float sy = sdv[di];
            union { _Float16 h[8]; v8h v; } Wg;
            #pragma unroll
            for (int j = 0; j < 4; j++) {
                Wg.h[j]     = (_Float16)(__expf(fmaf(S0[j], t, lc[j])) * sy);
                Wg.h[4 + j] = (_Float16)(__expf(fmaf(S1[j], t, lc[4 + j])) * sy);
            }
            const v8h Hh = *(const v8h*)(smem + (size_t)((pA * TP + prow) * HRH_COLS + 8 * g) * 2);
            const v8h Hl = *(const v8h*)(smem + (size_t)(((pA + 4) * TP + prow) * HRH_COLS + 8 * g) * 2);
            D2 = __builtin_amdgcn_mfma_f32_16x16x32_f16(Hh, Wg.v, D2, 0, 0, 0);
            D2 = __builtin_amdgcn_mfma_f32_16x16x32_f16(Hl, Wg.v, D2, 0, 0, 0);
        }
        if (l < 16) {   // lanes 0..15 hold D2 rows 0..3 = {x,y,z,wsum} for center c
            float rk = 1.f / fmaxf(D2[3], 1e-7f);   // reference floor: clip(wsum, 1e-7)
            if (stage < 3) {
                out4[(size_t)b * HW + (size_t)(h0 + row) * GWW + (w0 + c)] =
                    make_float4(D2[0] * rk, D2[1] * rk, D2[2] * rk, 0.f);
            } else {
                size_t obase = (size_t)b * 3 * HW + (size_t)(h0 + row) * GWW + (w0 + c);
                outP[obase]          = D2[0] * rk;
                outP[obase + HW]     = D2[1] * rk;
                outP[obase + 2 * HW] = D2[2] * rk;
            }
        }
    }
}

extern "C" void kernel_launch(void* const* d_in, const int* in_sizes, int n_in,
                              void* d_out, int out_size, void* d_ws, size_t ws_size,
                              hipStream_t stream) {
    const float* x      = (const float*)d_in[0];
    const float* guid   = (const float*)d_in[1];
    const float* lw     = (const float*)d_in[2];
    const float* lb     = (const float*)d_in[3];
    const float* w1s    = (const float*)d_in[4];
    const float* b1s    = (const float*)d_in[5];
    const float* w2s    = (const float*)d_in[6];
    const float* b2s    = (const float*)d_in[7];
    const float* temps  = (const float*)d_in[8];
    const float* sigmas = (const float*)d_in[9];

    char* ws = (char*)d_ws;
    const size_t P4_BYTES = (size_t)BATCH * HW * sizeof(float4);      // 6,422,528
    float4* guid4 = (float4*)ws;
    float4* hr4A  = (float4*)(ws + P4_BYTES);
    float4* hr4B  = (float4*)(ws + 2 * P4_BYTES);
    float*  f0    = (float*)(ws + 3 * P4_BYTES);                      // 31,104 B
    __half* wsB   = (__half*)(ws + 3 * P4_BYTES + 31104);             //  8,192 B
    __half* wsW1  = (__half*)(ws + 3 * P4_BYTES + 31104 + 8192);      //  1,024 B

    linear_prep_kernel<<<1946 + 1568, 256, 0, stream>>>(
        x, lw, lb, f0, w2s, wsB, w1s, b1s, wsW1, guid, guid4);
    bicubic_kernel<<<(BATCH * HW + 255) / 256, 256, 0, stream>>>(f0, hr4A);

    dim3 jgrid(14, 14, BATCH), jblock(16, 32);
    const float4* hins[4]  = { hr4A, hr4B, hr4A, hr4B };
    float4*       fouts[4] = { hr4B, hr4A, hr4B, nullptr };
    for (int s = 0; s < 4; s++) {
        jbu_kernel<<<jgrid, jblock, 0, stream>>>(
            guid4, wsW1, wsB, b2s + s * 32,
            hins[s], fouts[s], (s == 3) ? (float*)d_out : nullptr,
            temps, sigmas, s);
    }
}

// Round 7
// 292.545 us; speedup vs baseline: 1.0248x; 1.0248x over previous
//
#include <hip/hip_runtime.h>
#include <hip/hip_fp16.h>
#include <math.h>

#define GHH 224
#define GWW 224
#define HW (GHH*GWW)     // 50176
#define BATCH 8
#define RAD 3
#define DIAM 7
#define QC 32
#define TILE 16
#define TP (TILE + 2*RAD)   // 22
#define TPIX (TP*TP)        // 484
#define CS 485              // chunk-plane stride in float4 (proven layout)

// LDS layout: [hrh: 8 planes x 22 rows x 24 cols f16 = 8448 B][sq: 4*485*16 = 31040 B]
// hrh planes 0-3 = hi{x,y,z,1}, 4-7 = lo{x,y,z,0}. Total 39488 B -> 4 blocks/CU.
// R6 lesson: 512-thr/32-wave occupancy did NOT help (59.5 vs 56) -> back to 256 thr.
#define HRH_COLS 24
#define PSTR (TP*HRH_COLS)   // 528 halves per plane
#define HRH_B (8*PSTR*2)     // 8448 B
#define SMEM_B (HRH_B + 4*CS*16)  // 39488

#define L2E 1.44269504f

typedef _Float16 h2 __attribute__((ext_vector_type(2)));
typedef _Float16 v8h __attribute__((ext_vector_type(8)));
typedef float v4f __attribute__((ext_vector_type(4)));

__device__ __forceinline__ int refl(int i) {
    if (i < 0) i = -i;
    if (i >= GHH) i = 2 * GHH - 2 - i;
    return i;
}

__device__ __forceinline__ float gelu_fast(float v) {
    float u = 0.7978845608f * v * (1.f + 0.044715f * v * v);
    float e = __builtin_amdgcn_exp2f(u * (2.f * L2E));   // exp(2u), folded log2e
    float th = 1.f - 2.f / (e + 1.f);
    return 0.5f * v * (1.f + th);
}

// ---------------- linear + w2 B-frag prep + w1 f16 pack + guid4 pack ----------------
__global__ void linear_prep_kernel(const float* __restrict__ x,
                                   const float* __restrict__ W,
                                   const float* __restrict__ bias,
                                   float* __restrict__ f0,
                                   const float* __restrict__ w2s,
                                   __half* __restrict__ wsB,
                                   const float* __restrict__ w1s,
                                   const float* __restrict__ b1s,
                                   __half* __restrict__ wsW1,
                                   const float* __restrict__ guid,
                                   float4* __restrict__ guid4) {
    int blk = blockIdx.x;
    if (blk >= 1946) {   // guid4 pack: 1568 blocks
        int i = (blk - 1946) * 256 + threadIdx.x;
        int b = i / HW, pix = i % HW;
        guid4[i] = make_float4(guid[(b * 3) * HW + pix],
                               guid[(b * 3 + 1) * HW + pix],
                               guid[(b * 3 + 2) * HW + pix], 0.f);
        return;
    }
    if (blk == 1945) {   // pack w1/b1 (4 stages x 32 ch) into f16 quads (w0,w1,w2,b)
        int tid = threadIdx.x;
        if (tid < 128) {
            int s = tid >> 5, c = tid & 31;
            wsW1[tid * 4 + 0] = __float2half(w1s[s * 96 + c * 3 + 0]);
            wsW1[tid * 4 + 1] = __float2half(w1s[s * 96 + c * 3 + 1]);
            wsW1[tid * 4 + 2] = __float2half(w1s[s * 96 + c * 3 + 2]);
            wsW1[tid * 4 + 3] = __float2half(b1s[s * 32 + c]);
        }
        return;
    }
    if (blk == 1944) {   // pack w2 (4 stages) into f16 MFMA fragments
        int tid = threadIdx.x;
        int s = tid >> 6, l = tid & 63;
        int n0 = l & 15, kq = l >> 4;
        const float* w2 = w2s + s * 1024;
        __half* dst = wsB + (size_t)tid * 16;
        #pragma unroll
        for (int j = 0; j < 8; j++) {
            dst[j]     = __float2half(w2[n0 * QC + kq * 8 + j]);
            dst[8 + j] = __float2half(w2[(n0 + 16) * QC + kq * 8 + j]);
        }
        return;
    }
    int gwave = (blk * blockDim.x + threadIdx.x) >> 6;
    int lane = threadIdx.x & 63;
    if (gwave >= BATCH * 972) return;
    int b = gwave / 972, j = gwave % 972;
    const float* xr = x + b * 1000;
    const float* wr = W + j * 1000;
    float s = 0.f;
    for (int k = lane; k < 1000; k += 64)
        s += xr[k] * wr[k];
    #pragma unroll
    for (int off = 32; off; off >>= 1) s += __shfl_down(s, off, 64);
    if (lane == 0) f0[gwave] = s + bias[j];
}

// ---------------- bicubic 18 -> 224, float4-interleaved output ----------------
__device__ __forceinline__ float cubicw(float d) {
    d = fabsf(d);
    if (d <= 1.f) return ((1.25f * d - 2.25f) * d) * d + 1.f;
    if (d < 2.f)  return ((-0.75f * d + 3.75f) * d - 6.f) * d + 3.f;
    return 0.f;
}

__global__ void bicubic_kernel(const float* __restrict__ f0, float4* __restrict__ hr4) {
    int idx = blockIdx.x * blockDim.x + threadIdx.x;
    if (idx >= BATCH * HW) return;
    int pix = idx % HW;
    int b = idx / HW;
    int w = pix % GWW, h = pix / GWW;
    float xx = (w + 0.5f) * (18.f / 224.f) - 0.5f;
    float yy = (h + 0.5f) * (18.f / 224.f) - 0.5f;
    float fx0 = floorf(xx), fy0 = floorf(yy);
    int x0 = (int)fx0, y0 = (int)fy0;
    float tx = xx - fx0, ty = yy - fy0;
    float wx[4], wy[4];
    int ix[4], iy[4];
    #pragma unroll
    for (int k = 0; k < 4; k++) {
        wx[k] = cubicw(tx - (float)(k - 1));
        wy[k] = cubicw(ty - (float)(k - 1));
        int a = x0 + (k - 1); ix[k] = min(max(a, 0), 17);
        a = y0 + (k - 1);     iy[k] = min(max(a, 0), 17);
    }
    float acc[3];
    #pragma unroll
    for (int c = 0; c < 3; c++) {
        const float* src = f0 + (b * 3 + c) * 324;
        float a = 0.f;
        #pragma unroll
        for (int ky = 0; ky < 4; ky++) {
            float rowv = 0.f;
            #pragma unroll
            for (int kx = 0; kx < 4; kx++) rowv += wx[kx] * src[iy[ky] * 18 + ix[kx]];
            a += wy[ky] * rowv;
        }
        acc[c] = a;
    }
    hr4[idx] = make_float4(acc[0], acc[1], acc[2], 0.f);
}

// ---------------- fused JBU: MFMA scores + MFMA conv (R3 base, 256 threads) ----------------
// R7 deltas vs R3: (1) #pragma unroll 2 on the row loop -> 2 independent
// score->exp->conv chains in flight (duty); (2) log2e folded into exp constants
// (one VALU op deleted per transcendental, ~290 instr/thread).
__global__ __launch_bounds__(256, 4) void jbu_kernel(
    const float4* __restrict__ guid4,
    const __half* __restrict__ wsW1,
    const __half* __restrict__ wsB, const float* __restrict__ b2,
    const float4* __restrict__ hr4,
    float4* __restrict__ out4,
    float* __restrict__ outP,
    const float* __restrict__ temps,
    const float* __restrict__ sigmas,
    int stage)
{
    __shared__ __align__(16) char smem[SMEM_B];
    _Float16* hrh = (_Float16*)smem;            // [8][22][24] f16
    char* sqb = smem + HRH_B;                   // q tile f16 chunk-planar [4][CS] float4

    const int tx = threadIdx.x, ty = threadIdx.y;
    const int tid = ty * TILE + tx;
    const int b = blockIdx.z;
    const int h0 = blockIdx.y * TILE, w0 = blockIdx.x * TILE;

    // ---- stage hr tile as f16 hi/lo, channel-planar (+ ones / zeros planes) ----
    for (int i = tid; i < TPIX; i += 256) {
        int r = i / TP, cx = i % TP;
        int gh = refl(h0 - RAD + r), gw = refl(w0 - RAD + cx);
        float4 v = hr4[(size_t)b * HW + (size_t)gh * GWW + gw];
        _Float16 hx = (_Float16)v.x, hy = (_Float16)v.y, hz = (_Float16)v.z;
        int base = r * HRH_COLS + cx;
        hrh[0 * PSTR + base] = hx;
        hrh[1 * PSTR + base] = hy;
        hrh[2 * PSTR + base] = hz;
        hrh[3 * PSTR + base] = (_Float16)1.0f;
        hrh[4 * PSTR + base] = (_Float16)(v.x - (float)hx);
        hrh[5 * PSTR + base] = (_Float16)(v.y - (float)hy);
        hrh[6 * PSTR + base] = (_Float16)(v.z - (float)hz);
        hrh[7 * PSTR + base] = (_Float16)0.0f;
    }
    // zero pad cols 22,23 (read by masked-0 weights; must be finite, not LDS residue)
    for (int i = tid; i < 8 * TP * 2; i += 256) {
        int p = i / (TP * 2), rem = i % (TP * 2);
        int r = rem >> 1, cc = 22 + (rem & 1);
        hrh[p * PSTR + r * HRH_COLS + cc] = (_Float16)0.0f;
    }

    // ---- phase 0: q tile (R3-validated path) ----
    const int w = tid >> 6, l = tid & 63;
    const int n0 = l & 15, kq = l >> 4;
    const v8h* Bp = (const v8h*)(wsB + ((size_t)stage * 64 + l) * 16);
    const v8h W2a = Bp[0], W2b = Bp[1];
    const float4 b2a = *(const float4*)(b2 + 4 * kq);
    const float4 b2b = *(const float4*)(b2 + 16 + 4 * kq);
    union { _Float16 h[32]; float4 f4[4]; } W1;
    {
        const float4* wp = (const float4*)(wsW1 + stage * 128 + kq * 32);
        W1.f4[0] = wp[0]; W1.f4[1] = wp[1]; W1.f4[2] = wp[2]; W1.f4[3] = wp[3];
    }
    const int plane0 = kq >> 1;
    const int boff   = (kq & 1) * 8;

    #pragma unroll 1
    for (int r2 = 0; r2 < 2; r2++) {
        #pragma unroll
        for (int tt = 0; tt < 4; tt++) {
            int base = r2 * 256 + w * 64 + tt * 16;
            int p = base + n0;
            int pc = min(p, TPIX - 1);
            int rr = pc / TP, cc = pc - rr * TP;
            int gh = refl(h0 - RAD + rr), gw = refl(w0 - RAD + cc);
            float4 g = guid4[(size_t)b * HW + (size_t)gh * GWW + gw];
            union { _Float16 h[8]; v8h v; } A;
            #pragma unroll
            for (int j = 0; j < 8; j++) {
                float vv = fmaf((float)W1.h[j * 4], g.x,
                           fmaf((float)W1.h[j * 4 + 1], g.y,
                           fmaf((float)W1.h[j * 4 + 2], g.z, (float)W1.h[j * 4 + 3])));
                A.h[j] = (_Float16)gelu_fast(vv);
            }
            v4f D0 = {0.f, 0.f, 0.f, 0.f}, D1 = {0.f, 0.f, 0.f, 0.f};
            D0 = __builtin_amdgcn_mfma_f32_16x16x32_f16(W2a, A.v, D0, 0, 0, 0);
            D1 = __builtin_amdgcn_mfma_f32_16x16x32_f16(W2b, A.v, D1, 0, 0, 0);
            if (p < TPIX) {
                union { _Float16 h[4]; uint2 u; } q0, q1;
                q0.h[0] = (_Float16)(D0[0] + b2a.x);
                q0.h[1] = (_Float16)(D0[1] + b2a.y);
                q0.h[2] = (_Float16)(D0[2] + b2a.z);
                q0.h[3] = (_Float16)(D0[3] + b2a.w);
                q1.h[0] = (_Float16)(D1[0] + b2b.x);
                q1.h[1] = (_Float16)(D1[1] + b2b.y);
                q1.h[2] = (_Float16)(D1[2] + b2b.z);
                q1.h[3] = (_Float16)(D1[3] + b2b.w);
                *(uint2*)(sqb + (plane0 * CS + p) * 16 + boff)       = q0.u;
                *(uint2*)(sqb + ((2 + plane0) * CS + p) * 16 + boff) = q1.u;
            }
        }
    }
    __syncthreads();   // hrh + sq ready

    // ---- streaming: MFMA scores -> exp2 weights -> MFMA conv ----
    const int wv = tid >> 6;
    const int g = l >> 4, c = l & 15;      // g = k-chunk group, c = center col

    float t = __expf(temps[stage]);
    t = fminf(fmaxf(t, 1e-4f), 1e4f);
    const float tl2 = t * L2E;             // folded: exp(t*s+lc) = exp2(s*tl2 + lc2)
    float sig = sigmas[stage];
    float inv2s2 = 1.f / (2.f * sig * sig);
    float sdv[DIAM];
    #pragma unroll
    for (int i = 0; i < DIAM; i++) {
        float d = (float)(i - 3) * (1.f / 3.f);
        sdv[i] = __expf(-d * d * inv2s2);
    }
    // lc2[jj]: log2-domain spatial-x for tap k = 8g+jj at center c; -1.44e38 masks
    float lc2[8];
    #pragma unroll
    for (int jj = 0; jj < 8; jj++) {
        int dj = 8 * g + jj - c;
        float d = (float)(dj - 3) * (1.f / 3.f);
        lc2[jj] = (dj >= 0 && dj <= 6) ? (-d * d * inv2s2 * L2E) : -1.44e38f;
    }
    // neighbor-col loads (per lane, m = c): sigma_cb(c) clamped to row end
    const int nbb = 8 * (c >> 2) + (c & 3);
    const int nb0 = min(nbb, 21);
    const int nb1 = min(nbb + 4, 21);
    const int pA = c & 3;                  // hr channel plane for conv A-frag

    #pragma unroll 2
    for (int rr = 0; rr < 4; rr++) {
        const int row = wv * 4 + rr;
        // center B-frag (reused across di/cb): q[center row][col c][chunk g]
        const v8h Bc = *(const v8h*)(sqb + (size_t)(g * CS + (row + RAD) * TP + RAD + c) * 16);
        v4f D2 = {0.f, 0.f, 0.f, 0.f};
        #pragma unroll
        for (int di = 0; di < DIAM; di++) {
            const int prow = row + di;
            const v8h A0 = *(const v8h*)(sqb + (size_t)(g * CS + prow * TP + nb0) * 16);
            const v8h A1 = *(const v8h*)(sqb + (size_t)(g * CS + prow * TP + nb1) * 16);
            v4f S0 = {0.f, 0.f, 0.f, 0.f}, S1 = {0.f, 0.f, 0.f, 0.f};
            S0 = __builtin_amdgcn_mfma_f32_16x16x32_f16(A0, Bc, S0, 0, 0, 0);
            S1 = __builtin_amdgcn_mfma_f32_16x16x32_f16(A1, Bc, S1, 0, 0, 0);
            const float sy = sdv[di];
            union { _Float16 h[8]; v8h v; } Wg;
            #pragma unroll
            for (int j = 0; j < 4; j++) {
                Wg.h[j]     = (_Float16)(__builtin_amdgcn_exp2f(fmaf(S0[j], tl2, lc2[j])) * sy);
                Wg.h[4 + j] = (_Float16)(__builtin_amdgcn_exp2f(fmaf(S1[j], tl2, lc2[4 + j])) * sy);
            }
            const v8h Hh = *(const v8h*)(smem + (size_t)((pA * TP + prow) * HRH_COLS + 8 * g) * 2);
            const v8h Hl = *(const v8h*)(smem + (size_t)(((pA + 4) * TP + prow) * HRH_COLS + 8 * g) * 2);
            D2 = __builtin_amdgcn_mfma_f32_16x16x32_f16(Hh, Wg.v, D2, 0, 0, 0);
            D2 = __builtin_amdgcn_mfma_f32_16x16x32_f16(Hl, Wg.v, D2, 0, 0, 0);
        }
        if (l < 16) {   // lanes 0..15 hold D2 rows 0..3 = {x,y,z,wsum} for center c
            float rk = 1.f / fmaxf(D2[3], 1e-7f);   // reference floor: clip(wsum, 1e-7)
            if (stage < 3) {
                out4[(size_t)b * HW + (size_t)(h0 + row) * GWW + (w0 + c)] =
                    make_float4(D2[0] * rk, D2[1] * rk, D2[2] * rk, 0.f);
            } else {
                size_t obase = (size_t)b * 3 * HW + (size_t)(h0 + row) * GWW + (w0 + c);
                outP[obase]          = D2[0] * rk;
                outP[obase + HW]     = D2[1] * rk;
                outP[obase + 2 * HW] = D2[2] * rk;
            }
        }
    }
}

extern "C" void kernel_launch(void* const* d_in, const int* in_sizes, int n_in,
                              void* d_out, int out_size, void* d_ws, size_t ws_size,
                              hipStream_t stream) {
    const float* x      = (const float*)d_in[0];
    const float* guid   = (const float*)d_in[1];
    const float* lw     = (const float*)d_in[2];
    const float* lb     = (const float*)d_in[3];
    const float* w1s    = (const float*)d_in[4];
    const float* b1s    = (const float*)d_in[5];
    const float* w2s    = (const float*)d_in[6];
    const float* b2s    = (const float*)d_in[7];
    const float* temps  = (const float*)d_in[8];
    const float* sigmas = (const float*)d_in[9];

    char* ws = (char*)d_ws;
    const size_t P4_BYTES = (size_t)BATCH * HW * sizeof(float4);      // 6,422,528
    float4* guid4 = (float4*)ws;
    float4* hr4A  = (float4*)(ws + P4_BYTES);
    float4* hr4B  = (float4*)(ws + 2 * P4_BYTES);
    float*  f0    = (float*)(ws + 3 * P4_BYTES);                      // 31,104 B
    __half* wsB   = (__half*)(ws + 3 * P4_BYTES + 31104);             //  8,192 B
    __half* wsW1  = (__half*)(ws + 3 * P4_BYTES + 31104 + 8192);      //  1,024 B

    linear_prep_kernel<<<1946 + 1568, 256, 0, stream>>>(
        x, lw, lb, f0, w2s, wsB, w1s, b1s, wsW1, guid, guid4);
    bicubic_kernel<<<(BATCH * HW + 255) / 256, 256, 0, stream>>>(f0, hr4A);

    dim3 jgrid(14, 14, BATCH), jblock(16, 16);
    const float4* hins[4]  = { hr4A, hr4B, hr4A, hr4B };
    float4*       fouts[4] = { hr4B, hr4A, hr4B, nullptr };
    for (int s = 0; s < 4; s++) {
        jbu_kernel<<<jgrid, jblock, 0, stream>>>(
            guid4, wsW1, wsB, b2s + s * 32,
            hins[s], fouts[s], (s == 3) ? (float*)d_out : nullptr,
            temps, sigmas, s);
    }
}

// Round 8
// 279.227 us; speedup vs baseline: 1.0737x; 1.0477x over previous
//
#include <hip/hip_runtime.h>
#include <hip/hip_fp16.h>
#include <math.h>

#define GHH 224
#define GWW 224
#define HW (GHH*GWW)     // 50176
#define BATCH 8
#define RAD 3
#define DIAM 7
#define QC 32
#define TILE 16
#define TP (TILE + 2*RAD)   // 22
#define TPIX (TP*TP)        // 484
#define CS 485              // chunk-plane stride in float4 (proven layout)

// LDS layout: [hrh: 8 planes x 22 rows x 24 cols f16 = 8448 B][sq: 4*485*16 = 31040 B]
// hrh planes 0-3 = hi{x,y,z,1}, 4-7 = lo{x,y,z,0}. Total 39488 B -> 4 blocks/CU.
#define HRH_COLS 24
#define PSTR (TP*HRH_COLS)   // 528 halves per plane
#define HRH_B (8*PSTR*2)     // 8448 B
#define SMEM_B (HRH_B + 4*CS*16)  // 39488

#define L2E 1.44269504f

typedef _Float16 h2 __attribute__((ext_vector_type(2)));
typedef _Float16 v8h __attribute__((ext_vector_type(8)));
typedef float v4f __attribute__((ext_vector_type(4)));

__device__ __forceinline__ int refl(int i) {
    if (i < 0) i = -i;
    if (i >= GHH) i = 2 * GHH - 2 - i;
    return i;
}

__device__ __forceinline__ float gelu_fast(float v) {
    float u = 0.7978845608f * v * (1.f + 0.044715f * v * v);
    float e = __builtin_amdgcn_exp2f(u * (2.f * L2E));   // exp(2u), folded log2e
    float th = 1.f - 2.f / (e + 1.f);
    return 0.5f * v * (1.f + th);
}

// ---------------- linear + w2 B-frag prep + w1 f16 pack + guid4 pack ----------------
__global__ void linear_prep_kernel(const float* __restrict__ x,
                                   const float* __restrict__ W,
                                   const float* __restrict__ bias,
                                   float* __restrict__ f0,
                                   const float* __restrict__ w2s,
                                   __half* __restrict__ wsB,
                                   const float* __restrict__ w1s,
                                   const float* __restrict__ b1s,
                                   __half* __restrict__ wsW1,
                                   const float* __restrict__ guid,
                                   float4* __restrict__ guid4) {
    int blk = blockIdx.x;
    if (blk >= 1946) {   // guid4 pack: 1568 blocks
        int i = (blk - 1946) * 256 + threadIdx.x;
        int b = i / HW, pix = i % HW;
        guid4[i] = make_float4(guid[(b * 3) * HW + pix],
                               guid[(b * 3 + 1) * HW + pix],
                               guid[(b * 3 + 2) * HW + pix], 0.f);
        return;
    }
    if (blk == 1945) {   // pack w1/b1 (4 stages x 32 ch) into f16 quads (w0,w1,w2,b)
        int tid = threadIdx.x;
        if (tid < 128) {
            int s = tid >> 5, c = tid & 31;
            wsW1[tid * 4 + 0] = __float2half(w1s[s * 96 + c * 3 + 0]);
            wsW1[tid * 4 + 1] = __float2half(w1s[s * 96 + c * 3 + 1]);
            wsW1[tid * 4 + 2] = __float2half(w1s[s * 96 + c * 3 + 2]);
            wsW1[tid * 4 + 3] = __float2half(b1s[s * 32 + c]);
        }
        return;
    }
    if (blk == 1944) {   // pack w2 (4 stages) into f16 MFMA fragments
        int tid = threadIdx.x;
        int s = tid >> 6, l = tid & 63;
        int n0 = l & 15, kq = l >> 4;
        const float* w2 = w2s + s * 1024;
        __half* dst = wsB + (size_t)tid * 16;
        #pragma unroll
        for (int j = 0; j < 8; j++) {
            dst[j]     = __float2half(w2[n0 * QC + kq * 8 + j]);
            dst[8 + j] = __float2half(w2[(n0 + 16) * QC + kq * 8 + j]);
        }
        return;
    }
    int gwave = (blk * blockDim.x + threadIdx.x) >> 6;
    int lane = threadIdx.x & 63;
    if (gwave >= BATCH * 972) return;
    int b = gwave / 972, j = gwave % 972;
    const float* xr = x + b * 1000;
    const float* wr = W + j * 1000;
    float s = 0.f;
    for (int k = lane; k < 1000; k += 64)
        s += xr[k] * wr[k];
    #pragma unroll
    for (int off = 32; off; off >>= 1) s += __shfl_down(s, off, 64);
    if (lane == 0) f0[gwave] = s + bias[j];
}

// ---------------- bicubic 18 -> 224, float4-interleaved output ----------------
__device__ __forceinline__ float cubicw(float d) {
    d = fabsf(d);
    if (d <= 1.f) return ((1.25f * d - 2.25f) * d) * d + 1.f;
    if (d < 2.f)  return ((-0.75f * d + 3.75f) * d - 6.f) * d + 3.f;
    return 0.f;
}

__global__ void bicubic_kernel(const float* __restrict__ f0, float4* __restrict__ hr4) {
    int idx = blockIdx.x * blockDim.x + threadIdx.x;
    if (idx >= BATCH * HW) return;
    int pix = idx % HW;
    int b = idx / HW;
    int w = pix % GWW, h = pix / GWW;
    float xx = (w + 0.5f) * (18.f / 224.f) - 0.5f;
    float yy = (h + 0.5f) * (18.f / 224.f) - 0.5f;
    float fx0 = floorf(xx), fy0 = floorf(yy);
    int x0 = (int)fx0, y0 = (int)fy0;
    float tx = xx - fx0, ty = yy - fy0;
    float wx[4], wy[4];
    int ix[4], iy[4];
    #pragma unroll
    for (int k = 0; k < 4; k++) {
        wx[k] = cubicw(tx - (float)(k - 1));
        wy[k] = cubicw(ty - (float)(k - 1));
        int a = x0 + (k - 1); ix[k] = min(max(a, 0), 17);
        a = y0 + (k - 1);     iy[k] = min(max(a, 0), 17);
    }
    float acc[3];
    #pragma unroll
    for (int c = 0; c < 3; c++) {
        const float* src = f0 + (b * 3 + c) * 324;
        float a = 0.f;
        #pragma unroll
        for (int ky = 0; ky < 4; ky++) {
            float rowv = 0.f;
            #pragma unroll
            for (int kx = 0; kx < 4; kx++) rowv += wx[kx] * src[iy[ky] * 18 + ix[kx]];
            a += wy[ky] * rowv;
        }
        acc[c] = a;
    }
    hr4[idx] = make_float4(acc[0], acc[1], acc[2], 0.f);
}

// ---------------- q precompute: whole-image range_proj (phase-0 hoisted, 1x dup) ----------------
// Layout: qimg[(b*4 + P)*HW + pix] (float4 = 8 f16 = channels 8P..8P+7).
// Per wave: 8 iters x 16 px; lane (kq,n0) computes ch 4kq..4kq+3 (D0) and 16+4kq.. (D1)
// for its own pixel -> two 8B writes, exactly the validated phase-0 mapping.
__global__ __launch_bounds__(256) void q_kernel(
    const float4* __restrict__ guid4,
    const __half* __restrict__ wsW1,
    const __half* __restrict__ wsB, const float* __restrict__ b2,
    float4* __restrict__ qimg,
    int stage)
{
    const int tid = threadIdx.x;
    const int l = tid & 63;
    const int gw = (blockIdx.x * 256 + tid) >> 6;    // 0..3135 (784 blocks x 4 waves)
    const int n0 = l & 15, kq = l >> 4;
    const int b = gw / 392;                          // 392 waves per batch image
    const int pix0 = (gw - b * 392) * 128;

    const v8h* Bp = (const v8h*)(wsB + ((size_t)stage * 64 + l) * 16);
    const v8h W2a = Bp[0], W2b = Bp[1];
    const float4 b2a = *(const float4*)(b2 + 4 * kq);
    const float4 b2b = *(const float4*)(b2 + 16 + 4 * kq);
    union { _Float16 h[32]; float4 f4[4]; } W1;
    {
        const float4* wp = (const float4*)(wsW1 + stage * 128 + kq * 32);
        W1.f4[0] = wp[0]; W1.f4[1] = wp[1]; W1.f4[2] = wp[2]; W1.f4[3] = wp[3];
    }
    const int plane0 = kq >> 1;
    const int boff   = (kq & 1) * 8;
    char* qc = (char*)qimg;

    #pragma unroll 1
    for (int it = 0; it < 8; it++) {
        int pix = pix0 + it * 16 + n0;
        float4 g = guid4[(size_t)b * HW + pix];
        union { _Float16 h[8]; v8h v; } A;
        #pragma unroll
        for (int j = 0; j < 8; j++) {
            float vv = fmaf((float)W1.h[j * 4], g.x,
                       fmaf((float)W1.h[j * 4 + 1], g.y,
                       fmaf((float)W1.h[j * 4 + 2], g.z, (float)W1.h[j * 4 + 3])));
            A.h[j] = (_Float16)gelu_fast(vv);
        }
        v4f D0 = {0.f, 0.f, 0.f, 0.f}, D1 = {0.f, 0.f, 0.f, 0.f};
        D0 = __builtin_amdgcn_mfma_f32_16x16x32_f16(W2a, A.v, D0, 0, 0, 0);
        D1 = __builtin_amdgcn_mfma_f32_16x16x32_f16(W2b, A.v, D1, 0, 0, 0);
        union { _Float16 h[4]; uint2 u; } q0, q1;
        q0.h[0] = (_Float16)(D0[0] + b2a.x);
        q0.h[1] = (_Float16)(D0[1] + b2a.y);
        q0.h[2] = (_Float16)(D0[2] + b2a.z);
        q0.h[3] = (_Float16)(D0[3] + b2a.w);
        q1.h[0] = (_Float16)(D1[0] + b2b.x);
        q1.h[1] = (_Float16)(D1[1] + b2b.y);
        q1.h[2] = (_Float16)(D1[2] + b2b.z);
        q1.h[3] = (_Float16)(D1[3] + b2b.w);
        *(uint2*)(qc + ((size_t)(b * 4 + plane0) * HW + pix) * 16 + boff)     = q0.u;
        *(uint2*)(qc + ((size_t)(b * 4 + 2 + plane0) * HW + pix) * 16 + boff) = q1.u;
    }
}

// ---------------- fused JBU: stage q window -> MFMA scores -> exp2 -> MFMA conv ----------------
// Phase-0 replaced by a coalesced q-window stage (8 loads + 4 ds_write_b128 per thread,
// L2/L3-resident source). Streaming identical to R7 (exp2 weights, unroll 1, no spill).
__global__ __launch_bounds__(256, 4) void jbu_kernel(
    const float4* __restrict__ qimg,
    const float4* __restrict__ hr4,
    float4* __restrict__ out4,
    float* __restrict__ outP,
    const float* __restrict__ temps,
    const float* __restrict__ sigmas,
    int stage)
{
    __shared__ __align__(16) char smem[SMEM_B];
    _Float16* hrh = (_Float16*)smem;            // [8][22][24] f16
    char* sqb = smem + HRH_B;                   // q tile f16 chunk-planar [4][CS] float4
    float4* sqf4 = (float4*)sqb;

    const int tx = threadIdx.x, ty = threadIdx.y;
    const int tid = ty * TILE + tx;
    const int b = blockIdx.z;
    const int h0 = blockIdx.y * TILE, w0 = blockIdx.x * TILE;

    // ---- stage q window (4 planes) + hr tile (f16 hi/lo) from global ----
    const float4* qb = qimg + (size_t)b * 4 * HW;
    const float4* hb = hr4 + (size_t)b * HW;
    for (int i = tid; i < TPIX; i += 256) {
        int r = i / TP, cx = i % TP;
        int gh = refl(h0 - RAD + r), gw = refl(w0 - RAD + cx);
        size_t gpix = (size_t)gh * GWW + gw;
        sqf4[i]          = qb[gpix];
        sqf4[CS + i]     = qb[HW + gpix];
        sqf4[2 * CS + i] = qb[2 * HW + gpix];
        sqf4[3 * CS + i] = qb[3 * HW + gpix];
        float4 v = hb[gpix];
        _Float16 hx = (_Float16)v.x, hy = (_Float16)v.y, hz = (_Float16)v.z;
        int base = r * HRH_COLS + cx;
        hrh[0 * PSTR + base] = hx;
        hrh[1 * PSTR + base] = hy;
        hrh[2 * PSTR + base] = hz;
        hrh[3 * PSTR + base] = (_Float16)1.0f;
        hrh[4 * PSTR + base] = (_Float16)(v.x - (float)hx);
        hrh[5 * PSTR + base] = (_Float16)(v.y - (float)hy);
        hrh[6 * PSTR + base] = (_Float16)(v.z - (float)hz);
        hrh[7 * PSTR + base] = (_Float16)0.0f;
    }
    // zero pad cols 22,23 (read by masked-0 weights; must be finite, not LDS residue)
    for (int i = tid; i < 8 * TP * 2; i += 256) {
        int p = i / (TP * 2), rem = i % (TP * 2);
        int r = rem >> 1, cc = 22 + (rem & 1);
        hrh[p * PSTR + r * HRH_COLS + cc] = (_Float16)0.0f;
    }
    __syncthreads();   // hrh + sq ready

    // ---- streaming: MFMA scores -> exp2 weights -> MFMA conv (R3/R7-validated) ----
    const int wv = tid >> 6;
    const int l = tid & 63;
    const int g = l >> 4, c = l & 15;      // g = k-chunk group, c = center col

    float t = __expf(temps[stage]);
    t = fminf(fmaxf(t, 1e-4f), 1e4f);
    const float tl2 = t * L2E;             // folded: exp(t*s+lc) = exp2(s*tl2 + lc2)
    float sig = sigmas[stage];
    float inv2s2 = 1.f / (2.f * sig * sig);
    float sdv[DIAM];
    #pragma unroll
    for (int i = 0; i < DIAM; i++) {
        float d = (float)(i - 3) * (1.f / 3.f);
        sdv[i] = __expf(-d * d * inv2s2);
    }
    // lc2[jj]: log2-domain spatial-x for tap k = 8g+jj at center c; -1.44e38 masks
    float lc2[8];
    #pragma unroll
    for (int jj = 0; jj < 8; jj++) {
        int dj = 8 * g + jj - c;
        float d = (float)(dj - 3) * (1.f / 3.f);
        lc2[jj] = (dj >= 0 && dj <= 6) ? (-d * d * inv2s2 * L2E) : -1.44e38f;
    }
    // neighbor-col loads (per lane, m = c): sigma_cb(c) clamped to row end
    const int nbb = 8 * (c >> 2) + (c & 3);
    const int nb0 = min(nbb, 21);
    const int nb1 = min(nbb + 4, 21);
    const int pA = c & 3;                  // hr channel plane for conv A-frag

    #pragma unroll 1
    for (int rr = 0; rr < 4; rr++) {
        const int row = wv * 4 + rr;
        // center B-frag (reused across di/cb): q[center row][col c][chunk g]
        const v8h Bc = *(const v8h*)(sqb + (size_t)(g * CS + (row + RAD) * TP + RAD + c) * 16);
        v4f D2 = {0.f, 0.f, 0.f, 0.f};
        #pragma unroll
        for (int di = 0; di < DIAM; di++) {
            const int prow = row + di;
            const v8h A0 = *(const v8h*)(sqb + (size_t)(g * CS + prow * TP + nb0) * 16);
            const v8h A1 = *(const v8h*)(sqb + (size_t)(g * CS + prow * TP + nb1) * 16);
            v4f S0 = {0.f, 0.f, 0.f, 0.f}, S1 = {0.f, 0.f, 0.f, 0.f};
            S0 = __builtin_amdgcn_mfma_f32_16x16x32_f16(A0, Bc, S0, 0, 0, 0);
            S1 = __builtin_amdgcn_mfma_f32_16x16x32_f16(A1, Bc, S1, 0, 0, 0);
            const float sy = sdv[di];
            union { _Float16 h[8]; v8h v; } Wg;
            #pragma unroll
            for (int j = 0; j < 4; j++) {
                Wg.h[j]     = (_Float16)(__builtin_amdgcn_exp2f(fmaf(S0[j], tl2, lc2[j])) * sy);
                Wg.h[4 + j] = (_Float16)(__builtin_amdgcn_exp2f(fmaf(S1[j], tl2, lc2[4 + j])) * sy);
            }
            const v8h Hh = *(const v8h*)(smem + (size_t)((pA * TP + prow) * HRH_COLS + 8 * g) * 2);
            const v8h Hl = *(const v8h*)(smem + (size_t)(((pA + 4) * TP + prow) * HRH_COLS + 8 * g) * 2);
            D2 = __builtin_amdgcn_mfma_f32_16x16x32_f16(Hh, Wg.v, D2, 0, 0, 0);
            D2 = __builtin_amdgcn_mfma_f32_16x16x32_f16(Hl, Wg.v, D2, 0, 0, 0);
        }
        if (l < 16) {   // lanes 0..15 hold D2 rows 0..3 = {x,y,z,wsum} for center c
            float rk = 1.f / fmaxf(D2[3], 1e-7f);   // reference floor: clip(wsum, 1e-7)
            if (stage < 3) {
                out4[(size_t)b * HW + (size_t)(h0 + row) * GWW + (w0 + c)] =
                    make_float4(D2[0] * rk, D2[1] * rk, D2[2] * rk, 0.f);
            } else {
                size_t obase = (size_t)b * 3 * HW + (size_t)(h0 + row) * GWW + (w0 + c);
                outP[obase]          = D2[0] * rk;
                outP[obase + HW]     = D2[1] * rk;
                outP[obase + 2 * HW] = D2[2] * rk;
            }
        }
    }
}

extern "C" void kernel_launch(void* const* d_in, const int* in_sizes, int n_in,
                              void* d_out, int out_size, void* d_ws, size_t ws_size,
                              hipStream_t stream) {
    const float* x      = (const float*)d_in[0];
    const float* guid   = (const float*)d_in[1];
    const float* lw     = (const float*)d_in[2];
    const float* lb     = (const float*)d_in[3];
    const float* w1s    = (const float*)d_in[4];
    const float* b1s    = (const float*)d_in[5];
    const float* w2s    = (const float*)d_in[6];
    const float* b2s    = (const float*)d_in[7];
    const float* temps  = (const float*)d_in[8];
    const float* sigmas = (const float*)d_in[9];

    char* ws = (char*)d_ws;
    const size_t P4_BYTES = (size_t)BATCH * HW * sizeof(float4);      // 6,422,528
    float4* guid4 = (float4*)ws;
    float4* hr4A  = (float4*)(ws + P4_BYTES);
    float4* hr4B  = (float4*)(ws + 2 * P4_BYTES);
    float*  f0    = (float*)(ws + 3 * P4_BYTES);                      // 31,104 B
    __half* wsB   = (__half*)(ws + 3 * P4_BYTES + 31104);             //  8,192 B
    __half* wsW1  = (__half*)(ws + 3 * P4_BYTES + 31104 + 8192);      //  1,024 B
    float4* qimg  = (float4*)(ws + 3 * P4_BYTES + 40320);             // 25,690,112 B

    linear_prep_kernel<<<1946 + 1568, 256, 0, stream>>>(
        x, lw, lb, f0, w2s, wsB, w1s, b1s, wsW1, guid, guid4);
    bicubic_kernel<<<(BATCH * HW + 255) / 256, 256, 0, stream>>>(f0, hr4A);

    dim3 jgrid(14, 14, BATCH), jblock(16, 16);
    const float4* hins[4]  = { hr4A, hr4B, hr4A, hr4B };
    float4*       fouts[4] = { hr4B, hr4A, hr4B, nullptr };
    for (int s = 0; s < 4; s++) {
        q_kernel<<<784, 256, 0, stream>>>(guid4, wsW1, wsB, b2s + s * 32, qimg, s);
        jbu_kernel<<<jgrid, jblock, 0, stream>>>(
            qimg, hins[s], fouts[s], (s == 3) ? (float*)d_out : nullptr,
            temps, sigmas, s);
    }
}

// Round 9
// 278.607 us; speedup vs baseline: 1.0761x; 1.0022x over previous
//
#include <hip/hip_runtime.h>
#include <hip/hip_fp16.h>
#include <math.h>

#define GHH 224
#define GWW 224
#define HW (GHH*GWW)     // 50176
#define BATCH 8
#define RAD 3
#define DIAM 7
#define QC 32
#define TILE 16
#define TP (TILE + 2*RAD)   // 22
#define TPIX (TP*TP)        // 484
#define CS 485              // chunk-plane stride in float4 (proven layout)

// LDS layout: [hrh: 8 planes x 22 rows x 24 cols f16 = 8448 B][sq: 4*485*16 = 31040 B]
// hrh planes 0-3 = hi{x,y,z,1}, 4-7 = lo{x,y,z,0}. Total 39488 B -> 4 blocks/CU.
#define HRH_COLS 24
#define PSTR (TP*HRH_COLS)   // 528 halves per plane
#define HRH_B (8*PSTR*2)     // 8448 B
#define SMEM_B (HRH_B + 4*CS*16)  // 39488

#define L2E 1.44269504f

typedef _Float16 h2 __attribute__((ext_vector_type(2)));
typedef _Float16 v8h __attribute__((ext_vector_type(8)));
typedef float v4f __attribute__((ext_vector_type(4)));

__device__ __forceinline__ int refl(int i) {
    if (i < 0) i = -i;
    if (i >= GHH) i = 2 * GHH - 2 - i;
    return i;
}

__device__ __forceinline__ float gelu_fast(float v) {
    float u = 0.7978845608f * v * (1.f + 0.044715f * v * v);
    float e = __builtin_amdgcn_exp2f(u * (2.f * L2E));   // exp(2u), folded log2e
    float th = 1.f - 2.f / (e + 1.f);
    return 0.5f * v * (1.f + th);
}

// ---------------- linear + w2 B-frag prep + w1 f16 pack + guid4 pack ----------------
__global__ void linear_prep_kernel(const float* __restrict__ x,
                                   const float* __restrict__ W,
                                   const float* __restrict__ bias,
                                   float* __restrict__ f0,
                                   const float* __restrict__ w2s,
                                   __half* __restrict__ wsB,
                                   const float* __restrict__ w1s,
                                   const float* __restrict__ b1s,
                                   __half* __restrict__ wsW1,
                                   const float* __restrict__ guid,
                                   float4* __restrict__ guid4) {
    int blk = blockIdx.x;
    if (blk >= 1946) {   // guid4 pack: 1568 blocks
        int i = (blk - 1946) * 256 + threadIdx.x;
        int b = i / HW, pix = i % HW;
        guid4[i] = make_float4(guid[(b * 3) * HW + pix],
                               guid[(b * 3 + 1) * HW + pix],
                               guid[(b * 3 + 2) * HW + pix], 0.f);
        return;
    }
    if (blk == 1945) {   // pack w1/b1 (4 stages x 32 ch) into f16 quads (w0,w1,w2,b)
        int tid = threadIdx.x;
        if (tid < 128) {
            int s = tid >> 5, c = tid & 31;
            wsW1[tid * 4 + 0] = __float2half(w1s[s * 96 + c * 3 + 0]);
            wsW1[tid * 4 + 1] = __float2half(w1s[s * 96 + c * 3 + 1]);
            wsW1[tid * 4 + 2] = __float2half(w1s[s * 96 + c * 3 + 2]);
            wsW1[tid * 4 + 3] = __float2half(b1s[s * 32 + c]);
        }
        return;
    }
    if (blk == 1944) {   // pack w2 (4 stages) into f16 MFMA fragments
        int tid = threadIdx.x;
        int s = tid >> 6, l = tid & 63;
        int n0 = l & 15, kq = l >> 4;
        const float* w2 = w2s + s * 1024;
        __half* dst = wsB + (size_t)tid * 16;
        #pragma unroll
        for (int j = 0; j < 8; j++) {
            dst[j]     = __float2half(w2[n0 * QC + kq * 8 + j]);
            dst[8 + j] = __float2half(w2[(n0 + 16) * QC + kq * 8 + j]);
        }
        return;
    }
    int gwave = (blk * blockDim.x + threadIdx.x) >> 6;
    int lane = threadIdx.x & 63;
    if (gwave >= BATCH * 972) return;
    int b = gwave / 972, j = gwave % 972;
    const float* xr = x + b * 1000;
    const float* wr = W + j * 1000;
    float s = 0.f;
    for (int k = lane; k < 1000; k += 64)
        s += xr[k] * wr[k];
    #pragma unroll
    for (int off = 32; off; off >>= 1) s += __shfl_down(s, off, 64);
    if (lane == 0) f0[gwave] = s + bias[j];
}

// ---------------- bicubic 18 -> 224, float4-interleaved output ----------------
__device__ __forceinline__ float cubicw(float d) {
    d = fabsf(d);
    if (d <= 1.f) return ((1.25f * d - 2.25f) * d) * d + 1.f;
    if (d < 2.f)  return ((-0.75f * d + 3.75f) * d - 6.f) * d + 3.f;
    return 0.f;
}

__global__ void bicubic_kernel(const float* __restrict__ f0, float4* __restrict__ hr4) {
    int idx = blockIdx.x * blockDim.x + threadIdx.x;
    if (idx >= BATCH * HW) return;
    int pix = idx % HW;
    int b = idx / HW;
    int w = pix % GWW, h = pix / GWW;
    float xx = (w + 0.5f) * (18.f / 224.f) - 0.5f;
    float yy = (h + 0.5f) * (18.f / 224.f) - 0.5f;
    float fx0 = floorf(xx), fy0 = floorf(yy);
    int x0 = (int)fx0, y0 = (int)fy0;
    float tx = xx - fx0, ty = yy - fy0;
    float wx[4], wy[4];
    int ix[4], iy[4];
    #pragma unroll
    for (int k = 0; k < 4; k++) {
        wx[k] = cubicw(tx - (float)(k - 1));
        wy[k] = cubicw(ty - (float)(k - 1));
        int a = x0 + (k - 1); ix[k] = min(max(a, 0), 17);
        a = y0 + (k - 1);     iy[k] = min(max(a, 0), 17);
    }
    float acc[3];
    #pragma unroll
    for (int c = 0; c < 3; c++) {
        const float* src = f0 + (b * 3 + c) * 324;
        float a = 0.f;
        #pragma unroll
        for (int ky = 0; ky < 4; ky++) {
            float rowv = 0.f;
            #pragma unroll
            for (int kx = 0; kx < 4; kx++) rowv += wx[kx] * src[iy[ky] * 18 + ix[kx]];
            a += wy[ky] * rowv;
        }
        acc[c] = a;
    }
    hr4[idx] = make_float4(acc[0], acc[1], acc[2], 0.f);
}

// ---------------- q precompute: ALL 4 stages in one launch (phase-0 hoisted, 1x dup) ----------------
// Layout: qimg[((stage*BATCH + b)*4 + P)*HW + pix] (float4 = 8 f16 = ch 8P..8P+7).
// Grid (784, 4): blockIdx.y = stage. Per wave: 8 iters x 16 px, validated phase-0 mapping.
__global__ __launch_bounds__(256) void q_kernel(
    const float4* __restrict__ guid4,
    const __half* __restrict__ wsW1,
    const __half* __restrict__ wsB, const float* __restrict__ b2s,
    float4* __restrict__ qimg)
{
    const int stage = blockIdx.y;
    const float* b2 = b2s + stage * 32;
    const int tid = threadIdx.x;
    const int l = tid & 63;
    const int gw = (blockIdx.x * 256 + tid) >> 6;    // 0..3135 (784 blocks x 4 waves)
    const int n0 = l & 15, kq = l >> 4;
    const int b = gw / 392;                          // 392 waves per batch image
    const int pix0 = (gw - b * 392) * 128;

    const v8h* Bp = (const v8h*)(wsB + ((size_t)stage * 64 + l) * 16);
    const v8h W2a = Bp[0], W2b = Bp[1];
    const float4 b2a = *(const float4*)(b2 + 4 * kq);
    const float4 b2b = *(const float4*)(b2 + 16 + 4 * kq);
    union { _Float16 h[32]; float4 f4[4]; } W1;
    {
        const float4* wp = (const float4*)(wsW1 + stage * 128 + kq * 32);
        W1.f4[0] = wp[0]; W1.f4[1] = wp[1]; W1.f4[2] = wp[2]; W1.f4[3] = wp[3];
    }
    const int plane0 = kq >> 1;
    const int boff   = (kq & 1) * 8;
    char* qc = (char*)(qimg + (size_t)stage * BATCH * 4 * HW);

    #pragma unroll 1
    for (int it = 0; it < 8; it++) {
        int pix = pix0 + it * 16 + n0;
        float4 g = guid4[(size_t)b * HW + pix];
        union { _Float16 h[8]; v8h v; } A;
        #pragma unroll
        for (int j = 0; j < 8; j++) {
            float vv = fmaf((float)W1.h[j * 4], g.x,
                       fmaf((float)W1.h[j * 4 + 1], g.y,
                       fmaf((float)W1.h[j * 4 + 2], g.z, (float)W1.h[j * 4 + 3])));
            A.h[j] = (_Float16)gelu_fast(vv);
        }
        v4f D0 = {0.f, 0.f, 0.f, 0.f}, D1 = {0.f, 0.f, 0.f, 0.f};
        D0 = __builtin_amdgcn_mfma_f32_16x16x32_f16(W2a, A.v, D0, 0, 0, 0);
        D1 = __builtin_amdgcn_mfma_f32_16x16x32_f16(W2b, A.v, D1, 0, 0, 0);
        union { _Float16 h[4]; uint2 u; } q0, q1;
        q0.h[0] = (_Float16)(D0[0] + b2a.x);
        q0.h[1] = (_Float16)(D0[1] + b2a.y);
        q0.h[2] = (_Float16)(D0[2] + b2a.z);
        q0.h[3] = (_Float16)(D0[3] + b2a.w);
        q1.h[0] = (_Float16)(D1[0] + b2b.x);
        q1.h[1] = (_Float16)(D1[1] + b2b.y);
        q1.h[2] = (_Float16)(D1[2] + b2b.z);
        q1.h[3] = (_Float16)(D1[3] + b2b.w);
        *(uint2*)(qc + ((size_t)(b * 4 + plane0) * HW + pix) * 16 + boff)     = q0.u;
        *(uint2*)(qc + ((size_t)(b * 4 + 2 + plane0) * HW + pix) * 16 + boff) = q1.u;
    }
}

// ---------------- fused JBU: stage q window -> MFMA scores -> exp2 -> MFMA conv ----------------
// R9: #pragma unroll 2 on the row loop (phase-0 registers freed -> fits without spill;
// WRITE_SIZE is the spill falsifier). qimg pointer passed pre-offset per stage.
__global__ __launch_bounds__(256, 4) void jbu_kernel(
    const float4* __restrict__ qimg,
    const float4* __restrict__ hr4,
    float4* __restrict__ out4,
    float* __restrict__ outP,
    const float* __restrict__ temps,
    const float* __restrict__ sigmas,
    int stage)
{
    __shared__ __align__(16) char smem[SMEM_B];
    _Float16* hrh = (_Float16*)smem;            // [8][22][24] f16
    char* sqb = smem + HRH_B;                   // q tile f16 chunk-planar [4][CS] float4
    float4* sqf4 = (float4*)sqb;

    const int tx = threadIdx.x, ty = threadIdx.y;
    const int tid = ty * TILE + tx;
    const int b = blockIdx.z;
    const int h0 = blockIdx.y * TILE, w0 = blockIdx.x * TILE;

    // ---- stage q window (4 planes) + hr tile (f16 hi/lo) from global ----
    const float4* qb = qimg + (size_t)b * 4 * HW;
    const float4* hb = hr4 + (size_t)b * HW;
    for (int i = tid; i < TPIX; i += 256) {
        int r = i / TP, cx = i % TP;
        int gh = refl(h0 - RAD + r), gw = refl(w0 - RAD + cx);
        size_t gpix = (size_t)gh * GWW + gw;
        sqf4[i]          = qb[gpix];
        sqf4[CS + i]     = qb[HW + gpix];
        sqf4[2 * CS + i] = qb[2 * HW + gpix];
        sqf4[3 * CS + i] = qb[3 * HW + gpix];
        float4 v = hb[gpix];
        _Float16 hx = (_Float16)v.x, hy = (_Float16)v.y, hz = (_Float16)v.z;
        int base = r * HRH_COLS + cx;
        hrh[0 * PSTR + base] = hx;
        hrh[1 * PSTR + base] = hy;
        hrh[2 * PSTR + base] = hz;
        hrh[3 * PSTR + base] = (_Float16)1.0f;
        hrh[4 * PSTR + base] = (_Float16)(v.x - (float)hx);
        hrh[5 * PSTR + base] = (_Float16)(v.y - (float)hy);
        hrh[6 * PSTR + base] = (_Float16)(v.z - (float)hz);
        hrh[7 * PSTR + base] = (_Float16)0.0f;
    }
    // zero pad cols 22,23 (read by masked-0 weights; must be finite, not LDS residue)
    for (int i = tid; i < 8 * TP * 2; i += 256) {
        int p = i / (TP * 2), rem = i % (TP * 2);
        int r = rem >> 1, cc = 22 + (rem & 1);
        hrh[p * PSTR + r * HRH_COLS + cc] = (_Float16)0.0f;
    }
    __syncthreads();   // hrh + sq ready

    // ---- streaming: MFMA scores -> exp2 weights -> MFMA conv ----
    const int wv = tid >> 6;
    const int l = tid & 63;
    const int g = l >> 4, c = l & 15;      // g = k-chunk group, c = center col

    float t = __expf(temps[stage]);
    t = fminf(fmaxf(t, 1e-4f), 1e4f);
    const float tl2 = t * L2E;             // folded: exp(t*s+lc) = exp2(s*tl2 + lc2)
    float sig = sigmas[stage];
    float inv2s2 = 1.f / (2.f * sig * sig);
    float sdv[DIAM];
    #pragma unroll
    for (int i = 0; i < DIAM; i++) {
        float d = (float)(i - 3) * (1.f / 3.f);
        sdv[i] = __expf(-d * d * inv2s2);
    }
    // lc2[jj]: log2-domain spatial-x for tap k = 8g+jj at center c; -1.44e38 masks
    float lc2[8];
    #pragma unroll
    for (int jj = 0; jj < 8; jj++) {
        int dj = 8 * g + jj - c;
        float d = (float)(dj - 3) * (1.f / 3.f);
        lc2[jj] = (dj >= 0 && dj <= 6) ? (-d * d * inv2s2 * L2E) : -1.44e38f;
    }
    // neighbor-col loads (per lane, m = c): sigma_cb(c) clamped to row end
    const int nbb = 8 * (c >> 2) + (c & 3);
    const int nb0 = min(nbb, 21);
    const int nb1 = min(nbb + 4, 21);
    const int pA = c & 3;                  // hr channel plane for conv A-frag

    #pragma unroll 2
    for (int rr = 0; rr < 4; rr++) {
        const int row = wv * 4 + rr;
        // center B-frag (reused across di/cb): q[center row][col c][chunk g]
        const v8h Bc = *(const v8h*)(sqb + (size_t)(g * CS + (row + RAD) * TP + RAD + c) * 16);
        v4f D2 = {0.f, 0.f, 0.f, 0.f};
        #pragma unroll
        for (int di = 0; di < DIAM; di++) {
            const int prow = row + di;
            const v8h A0 = *(const v8h*)(sqb + (size_t)(g * CS + prow * TP + nb0) * 16);
            const v8h A1 = *(const v8h*)(sqb + (size_t)(g * CS + prow * TP + nb1) * 16);
            v4f S0 = {0.f, 0.f, 0.f, 0.f}, S1 = {0.f, 0.f, 0.f, 0.f};
            S0 = __builtin_amdgcn_mfma_f32_16x16x32_f16(A0, Bc, S0, 0, 0, 0);
            S1 = __builtin_amdgcn_mfma_f32_16x16x32_f16(A1, Bc, S1, 0, 0, 0);
            const float sy = sdv[di];
            union { _Float16 h[8]; v8h v; } Wg;
            #pragma unroll
            for (int j = 0; j < 4; j++) {
                Wg.h[j]     = (_Float16)(__builtin_amdgcn_exp2f(fmaf(S0[j], tl2, lc2[j])) * sy);
                Wg.h[4 + j] = (_Float16)(__builtin_amdgcn_exp2f(fmaf(S1[j], tl2, lc2[4 + j])) * sy);
            }
            const v8h Hh = *(const v8h*)(smem + (size_t)((pA * TP + prow) * HRH_COLS + 8 * g) * 2);
            const v8h Hl = *(const v8h*)(smem + (size_t)(((pA + 4) * TP + prow) * HRH_COLS + 8 * g) * 2);
            D2 = __builtin_amdgcn_mfma_f32_16x16x32_f16(Hh, Wg.v, D2, 0, 0, 0);
            D2 = __builtin_amdgcn_mfma_f32_16x16x32_f16(Hl, Wg.v, D2, 0, 0, 0);
        }
        if (l < 16) {   // lanes 0..15 hold D2 rows 0..3 = {x,y,z,wsum} for center c
            float rk = 1.f / fmaxf(D2[3], 1e-7f);   // reference floor: clip(wsum, 1e-7)
            if (stage < 3) {
                out4[(size_t)b * HW + (size_t)(h0 + row) * GWW + (w0 + c)] =
                    make_float4(D2[0] * rk, D2[1] * rk, D2[2] * rk, 0.f);
            } else {
                size_t obase = (size_t)b * 3 * HW + (size_t)(h0 + row) * GWW + (w0 + c);
                outP[obase]          = D2[0] * rk;
                outP[obase + HW]     = D2[1] * rk;
                outP[obase + 2 * HW] = D2[2] * rk;
            }
        }
    }
}

extern "C" void kernel_launch(void* const* d_in, const int* in_sizes, int n_in,
                              void* d_out, int out_size, void* d_ws, size_t ws_size,
                              hipStream_t stream) {
    const float* x      = (const float*)d_in[0];
    const float* guid   = (const float*)d_in[1];
    const float* lw     = (const float*)d_in[2];
    const float* lb     = (const float*)d_in[3];
    const float* w1s    = (const float*)d_in[4];
    const float* b1s    = (const float*)d_in[5];
    const float* w2s    = (const float*)d_in[6];
    const float* b2s    = (const float*)d_in[7];
    const float* temps  = (const float*)d_in[8];
    const float* sigmas = (const float*)d_in[9];

    char* ws = (char*)d_ws;
    const size_t P4_BYTES = (size_t)BATCH * HW * sizeof(float4);      // 6,422,528
    float4* guid4 = (float4*)ws;
    float4* hr4A  = (float4*)(ws + P4_BYTES);
    float4* hr4B  = (float4*)(ws + 2 * P4_BYTES);
    float*  f0    = (float*)(ws + 3 * P4_BYTES);                      // 31,104 B
    __half* wsB   = (__half*)(ws + 3 * P4_BYTES + 31104);             //  8,192 B
    __half* wsW1  = (__half*)(ws + 3 * P4_BYTES + 31104 + 8192);      //  1,024 B
    float4* qimg  = (float4*)(ws + 3 * P4_BYTES + 40320);             // 4 stages x 25,690,112 B

    linear_prep_kernel<<<1946 + 1568, 256, 0, stream>>>(
        x, lw, lb, f0, w2s, wsB, w1s, b1s, wsW1, guid, guid4);
    q_kernel<<<dim3(784, 4), 256, 0, stream>>>(guid4, wsW1, wsB, b2s, qimg);
    bicubic_kernel<<<(BATCH * HW + 255) / 256, 256, 0, stream>>>(f0, hr4A);

    dim3 jgrid(14, 14, BATCH), jblock(16, 16);
    const float4* hins[4]  = { hr4A, hr4B, hr4A, hr4B };
    float4*       fouts[4] = { hr4B, hr4A, hr4B, nullptr };
    for (int s = 0; s < 4; s++) {
        jbu_kernel<<<jgrid, jblock, 0, stream>>>(
            qimg + (size_t)s * BATCH * 4 * HW,
            hins[s], fouts[s], (s == 3) ? (float*)d_out : nullptr,
            temps, sigmas, s);
    }
}